// Round 1
// baseline (752.649 us; speedup 1.0000x reference)
//
#include <hip/hip_runtime.h>
#include <cmath>

constexpr int kB  = 8;
constexpr int kC  = 256;
constexpr int kH  = 64;
constexpr int kW  = 64;
constexpr int kP  = kH * kW;    // 4096
constexpr int kL  = 80;
constexpr int kD  = 256;
constexpr int kNH = 8;

// ---------------------------------------------------------------------------
// Kernel 0: transpose conv_w (co, ci, 3, 3) -> wT[ci][tap][co]
// so that conv weight staging loads are coalesced over co.
// ---------------------------------------------------------------------------
__global__ __launch_bounds__(256) void transpose_w_kernel(
    const float* __restrict__ cw, float* __restrict__ wT) {
  int idx = blockIdx.x * 256 + threadIdx.x;  // over ci*9*co = 589824
  if (idx >= kC * 9 * kC) return;
  int co  = idx & 255;
  int tmp = idx >> 8;        // ci*9 + tap
  int tap = tmp % 9;
  int ci  = tmp / 9;
  wT[idx] = cw[co * (kC * 9) + ci * 9 + tap];
}

// ---------------------------------------------------------------------------
// Kernel 1: fused 1x1 conv (GEMM) + max-over-tokens attention.
// Block tile: 64 pixels x 64 channels (= 2 heads). 256 threads, 4x4 micro.
// Writes attn (B, 8, P) fp32 into workspace.
// ---------------------------------------------------------------------------
__global__ __launch_bounds__(256) void attn_kernel(
    const float* __restrict__ img,   // (B, C, H, W)
    const float* __restrict__ text,  // (B, L, D)
    const float* __restrict__ pw,    // (D, C)
    const float* __restrict__ pb,    // (D,)
    const float* __restrict__ bias,  // (NH,)
    const float* __restrict__ scale, // (NH,)
    float* __restrict__ attn_out) {  // (B, NH, P)
  __shared__ float As[16][64];   // [c][pixel]
  __shared__ float Bs[16][68];   // [c][d]  (padded)
  __shared__ float S[64][68];    // i_feat tile [pixel][d] (padded)
  __shared__ float Ts[80][68];   // text tile [n][d] (padded)

  const int b  = blockIdx.x;       // batch
  const int p0 = blockIdx.y * 64;  // pixel tile
  const int z  = blockIdx.z;       // head pair (d-tile of 64)
  const int d0 = z * 64;
  const int t  = threadIdx.x;
  const int tx = t & 15;           // d micro index
  const int ty = t >> 4;           // pixel micro index

  const float* imgb = img + (size_t)b * kC * kP;

  float acc[4][4] = {};

  for (int c0 = 0; c0 < kC; c0 += 16) {
    __syncthreads();
    // stage As: 16 c x 64 px  (coalesced over pixels)
    {
      int e = t;
#pragma unroll
      for (int i = 0; i < 4; i++, e += 256) {
        int cc = e >> 6, pp = e & 63;
        As[cc][pp] = imgb[(c0 + cc) * kP + p0 + pp];
      }
    }
    // stage Bs: transpose-in-LDS of pw[d][c]
    {
      int e = t;
#pragma unroll
      for (int i = 0; i < 4; i++, e += 256) {
        int dd = e >> 4, cc = e & 15;
        Bs[cc][dd] = pw[(d0 + dd) * kC + c0 + cc];
      }
    }
    __syncthreads();
#pragma unroll
    for (int kk = 0; kk < 16; kk++) {
      float4 a = *(const float4*)&As[kk][ty * 4];
      float4 w = *(const float4*)&Bs[kk][tx * 4];
      acc[0][0] += a.x * w.x; acc[0][1] += a.x * w.y; acc[0][2] += a.x * w.z; acc[0][3] += a.x * w.w;
      acc[1][0] += a.y * w.x; acc[1][1] += a.y * w.y; acc[1][2] += a.y * w.z; acc[1][3] += a.y * w.w;
      acc[2][0] += a.z * w.x; acc[2][1] += a.z * w.y; acc[2][2] += a.z * w.z; acc[2][3] += a.z * w.w;
      acc[3][0] += a.w * w.x; acc[3][1] += a.w * w.y; acc[3][2] += a.w * w.z; acc[3][3] += a.w * w.w;
    }
  }

  // write i_feat tile (+ proj bias) to LDS; stage text slice
  {
    float4 pb4 = *(const float4*)(pb + d0 + tx * 4);
#pragma unroll
    for (int i = 0; i < 4; i++) {
      float4 v;
      v.x = acc[i][0] + pb4.x;
      v.y = acc[i][1] + pb4.y;
      v.z = acc[i][2] + pb4.z;
      v.w = acc[i][3] + pb4.w;
      *(float4*)&S[ty * 4 + i][tx * 4] = v;
    }
    const float* textb = text + (size_t)b * kL * kD + d0;
    int e = t;
#pragma unroll
    for (int i = 0; i < 20; i++, e += 256) {  // 80*64 = 5120 = 20*256
      int n = e >> 6, dd = e & 63;
      Ts[n][dd] = textb[n * kD + dd];
    }
  }
  __syncthreads();

  // attention: 128 (pixel, head) tasks, 2 threads each split the 80 tokens
  {
    const int task = t >> 1;
    const int half = t & 1;
    const int pp   = task & 63;
    const int mh   = task >> 6;  // 0 or 1 within the head pair

    float4 sv[8];
    const float* Srow = &S[pp][mh * 32];
#pragma unroll
    for (int c4 = 0; c4 < 8; c4++) sv[c4] = *(const float4*)(Srow + c4 * 4);

    float best = -3.4e38f;
    const int n0 = half * 40;
    for (int n = n0; n < n0 + 40; n++) {
      const float* Trow = &Ts[n][mh * 32];
      float sum = 0.f;
#pragma unroll
      for (int c4 = 0; c4 < 8; c4++) {
        float4 tv = *(const float4*)(Trow + c4 * 4);
        sum += sv[c4].x * tv.x + sv[c4].y * tv.y + sv[c4].z * tv.z + sv[c4].w * tv.w;
      }
      best = fmaxf(best, sum);
    }
    best = fmaxf(best, __shfl_xor(best, 1));
    if (half == 0) {
      const int m = z * 2 + mh;
      float v = best * 0.17677669529663687f + bias[m];  // 1/sqrt(32)
      v = scale[m] / (1.0f + expf(-v));
      attn_out[((size_t)b * kNH + m) * kP + p0 + pp] = v;
    }
  }
}

// ---------------------------------------------------------------------------
// Kernel 2: 3x3 conv (pad 1, no bias) + BN (inference) + per-head attn gate.
// Block: 1 batch, 2 rows x 64 cols = 128 px, 64 co. 256 threads.
// Each thread: 4 co x 8 px. ci staged in chunks of 8.
// ---------------------------------------------------------------------------
__global__ __launch_bounds__(256) void conv_kernel(
    const float* __restrict__ img,    // (B, C, H, W)
    const float* __restrict__ wT,     // [ci][tap][co]
    const float* __restrict__ gamma,
    const float* __restrict__ beta,
    const float* __restrict__ mean,
    const float* __restrict__ var,
    const float* __restrict__ attn,   // (B, NH, P)
    float* __restrict__ out) {        // (B, C, H, W)
  __shared__ float Is[8 * 4 * 68];    // 8 ci x 4 rows x 68 cols (66 valid)
  __shared__ float Ws[8 * 9 * 64];    // 8 ci x 9 taps x 64 co

  const int b   = blockIdx.x;        // 8
  const int h0  = blockIdx.y * 2;    // 32 row-pair tiles
  const int co0 = blockIdx.z * 64;   // 4 co tiles
  const int t   = threadIdx.x;
  const int tx  = t & 15;
  const int ty  = t >> 4;
  const int hh  = tx >> 3;           // which of the 2 rows
  const int w0  = (tx & 7) * 8;      // 8-px column group

  const float* imgb = img + (size_t)b * kC * kP;

  float acc[4][8] = {};

  for (int c0 = 0; c0 < kC; c0 += 8) {
    __syncthreads();
    // stage img halo tile: 8 ci x 4 rows (h0-1..h0+2) x 66 cols (-1..64)
    for (int e = t; e < 8 * 4 * 66; e += 256) {
      int cc = e % 66;
      int r  = (e / 66) & 3;
      int ci = e / 264;
      int h  = h0 - 1 + r;
      int w  = cc - 1;
      float v = 0.f;
      if (h >= 0 && h < kH && w >= 0 && w < kW)
        v = imgb[(c0 + ci) * kP + h * kW + w];
      Is[(ci * 4 + r) * 68 + cc] = v;
    }
    // stage weights: 8 ci x 9 taps x 64 co (coalesced over co via wT)
    {
      int e = t;
#pragma unroll
      for (int i = 0; i < 18; i++, e += 256) {  // 4608 = 18*256
        int ci  = e / 576;
        int r   = e - ci * 576;
        int tap = r >> 6;
        int co  = r & 63;
        Ws[e] = wT[((c0 + ci) * 9 + tap) * kC + co0 + co];
      }
    }
    __syncthreads();
#pragma unroll
    for (int ci = 0; ci < 8; ci++) {
#pragma unroll
      for (int kh = 0; kh < 3; kh++) {
        const float* rowp = &Is[(ci * 4 + hh + kh) * 68 + w0];
        float win[12];
        *(float4*)&win[0] = *(const float4*)(rowp);
        *(float4*)&win[4] = *(const float4*)(rowp + 4);
        *(float4*)&win[8] = *(const float4*)(rowp + 8);
#pragma unroll
        for (int kw = 0; kw < 3; kw++) {
          float4 wv = *(const float4*)&Ws[(ci * 9 + kh * 3 + kw) * 64 + ty * 4];
#pragma unroll
          for (int j = 0; j < 8; j++) {
            float xv = win[j + kw];
            acc[0][j] += wv.x * xv;
            acc[1][j] += wv.y * xv;
            acc[2][j] += wv.z * xv;
            acc[3][j] += wv.w * xv;
          }
        }
      }
    }
  }

  // epilogue: BN affine + attn gate, vectorized stores
  const int prow = (h0 + hh) * kW + w0;
  const int m    = (co0 >> 5) + ((ty * 4) >> 5);  // head (uniform over cc)
  const float* arow = attn + ((size_t)b * kNH + m) * kP + prow;
  float4 a0 = *(const float4*)(arow);
  float4 a1 = *(const float4*)(arow + 4);
  float av[8] = {a0.x, a0.y, a0.z, a0.w, a1.x, a1.y, a1.z, a1.w};

  float* outb = out + (size_t)b * kC * kP;
#pragma unroll
  for (int cc = 0; cc < 4; cc++) {
    int co = co0 + ty * 4 + cc;
    float inv = gamma[co] * rsqrtf(var[co] + 1e-3f);
    float bb  = beta[co] - mean[co] * inv;
    float4 o0, o1;
    o0.x = (acc[cc][0] * inv + bb) * av[0];
    o0.y = (acc[cc][1] * inv + bb) * av[1];
    o0.z = (acc[cc][2] * inv + bb) * av[2];
    o0.w = (acc[cc][3] * inv + bb) * av[3];
    o1.x = (acc[cc][4] * inv + bb) * av[4];
    o1.y = (acc[cc][5] * inv + bb) * av[5];
    o1.z = (acc[cc][6] * inv + bb) * av[6];
    o1.w = (acc[cc][7] * inv + bb) * av[7];
    *(float4*)(outb + (size_t)co * kP + prow)     = o0;
    *(float4*)(outb + (size_t)co * kP + prow + 4) = o1;
  }
}

// ---------------------------------------------------------------------------
extern "C" void kernel_launch(void* const* d_in, const int* in_sizes, int n_in,
                              void* d_out, int out_size, void* d_ws, size_t ws_size,
                              hipStream_t stream) {
  const float* img   = (const float*)d_in[0];
  const float* text  = (const float*)d_in[1];
  const float* pw    = (const float*)d_in[2];
  const float* pb    = (const float*)d_in[3];
  const float* bias  = (const float*)d_in[4];
  const float* scale = (const float*)d_in[5];
  const float* cw    = (const float*)d_in[6];
  const float* gam   = (const float*)d_in[7];
  const float* bet   = (const float*)d_in[8];
  const float* mea   = (const float*)d_in[9];
  const float* va    = (const float*)d_in[10];
  float* out = (float*)d_out;

  float* ws_f  = (float*)d_ws;
  float* attn  = ws_f;                          // B*NH*P floats = 1 MB
  float* wT    = ws_f + (size_t)kB * kNH * kP;  // C*9*C floats = 2.36 MB

  // transpose conv weights
  transpose_w_kernel<<<(kC * 9 * kC) / 256, 256, 0, stream>>>(cw, wT);

  // attention map
  {
    dim3 grid(kB, kP / 64, 4);
    attn_kernel<<<grid, 256, 0, stream>>>(img, text, pw, pb, bias, scale, attn);
  }

  // 3x3 conv + BN + gate
  {
    dim3 grid(kB, kH / 2, kC / 64);
    conv_kernel<<<grid, 256, 0, stream>>>(img, wT, gam, bet, mea, va, attn, out);
  }
}

// Round 2
// 275.862 us; speedup vs baseline: 2.7283x; 2.7283x over previous
//
#include <hip/hip_runtime.h>
#include <cmath>

constexpr int kB  = 8;
constexpr int kC  = 256;
constexpr int kH  = 64;
constexpr int kW  = 64;
constexpr int kP  = kH * kW;    // 4096
constexpr int kL  = 80;
constexpr int kD  = 256;
constexpr int kNH = 8;

typedef short  short8 __attribute__((ext_vector_type(8)));
typedef float  f32x4  __attribute__((ext_vector_type(4)));
typedef unsigned short ushort_t;

// round-to-nearest-even f32 -> bf16 bits (inputs are finite randoms; NaN path skipped)
__device__ __forceinline__ ushort_t f2bf(float f) {
  unsigned u = __builtin_bit_cast(unsigned, f);
  u += 0x7fffu + ((u >> 16) & 1u);
  return (ushort_t)(u >> 16);
}

// ---------------------------------------------------------------------------
// Kernel A: img (B, C, H, W) fp32  ->  imgT (B, P, C) bf16   (NHWC cast)
// Tile: 64 ci x 64 px per block via LDS.
// ---------------------------------------------------------------------------
__global__ __launch_bounds__(256) void transpose_img_kernel(
    const float* __restrict__ img, ushort_t* __restrict__ imgT) {
  __shared__ float Ls[64 * 67];   // [px][ci], pad 67 (bank stride 3 -> conflict-free)
  const int b   = blockIdx.x;
  const int p0  = blockIdx.y * 64;
  const int ci0 = blockIdx.z * 64;
  const int t   = threadIdx.x;

  // load 64 ci x 64 px, coalesced over px
  for (int e = t; e < 4096; e += 256) {
    int ci = e >> 6, px = e & 63;
    Ls[px * 67 + ci] = img[((size_t)(b * kC + ci0 + ci)) * kP + p0 + px];
  }
  __syncthreads();
  // store: each unit = 8 consecutive ci of one px (16 B)
  for (int u = t; u < 512; u += 256) {
    int px = u >> 3, cq = (u & 7) * 8;
    ushort_t tmp[8];
#pragma unroll
    for (int j = 0; j < 8; j++) tmp[j] = f2bf(Ls[px * 67 + cq + j]);
    *(uint4*)&imgT[((size_t)(b * kP + p0 + px)) * kC + ci0 + cq] = *(uint4*)tmp;
  }
}

// ---------------------------------------------------------------------------
// Kernel B: conv_w (co, ci, 3, 3) fp32 -> w2[tap][co][ci] bf16
// ---------------------------------------------------------------------------
__global__ __launch_bounds__(256) void transpose_w2_kernel(
    const float* __restrict__ cw, ushort_t* __restrict__ w2) {
  int idx = blockIdx.x * 256 + threadIdx.x;   // 9*256*256 = 589824
  if (idx >= 9 * kC * kC) return;
  int ci  = idx & 255;
  int co  = (idx >> 8) & 255;
  int tap = idx >> 16;
  w2[idx] = f2bf(cw[(co * kC + ci) * 9 + tap]);
}

// ---------------------------------------------------------------------------
// Kernel 1 (unchanged): fused 1x1 conv (GEMM) + max-over-tokens attention.
// ---------------------------------------------------------------------------
__global__ __launch_bounds__(256) void attn_kernel(
    const float* __restrict__ img,   // (B, C, H, W)
    const float* __restrict__ text,  // (B, L, D)
    const float* __restrict__ pw,    // (D, C)
    const float* __restrict__ pb,    // (D,)
    const float* __restrict__ bias,  // (NH,)
    const float* __restrict__ scale, // (NH,)
    float* __restrict__ attn_out) {  // (B, NH, P)
  __shared__ float As[16][64];
  __shared__ float Bs[16][68];
  __shared__ float S[64][68];
  __shared__ float Ts[80][68];

  const int b  = blockIdx.x;
  const int p0 = blockIdx.y * 64;
  const int z  = blockIdx.z;
  const int d0 = z * 64;
  const int t  = threadIdx.x;
  const int tx = t & 15;
  const int ty = t >> 4;

  const float* imgb = img + (size_t)b * kC * kP;

  float acc[4][4] = {};

  for (int c0 = 0; c0 < kC; c0 += 16) {
    __syncthreads();
    {
      int e = t;
#pragma unroll
      for (int i = 0; i < 4; i++, e += 256) {
        int cc = e >> 6, pp = e & 63;
        As[cc][pp] = imgb[(c0 + cc) * kP + p0 + pp];
      }
    }
    {
      int e = t;
#pragma unroll
      for (int i = 0; i < 4; i++, e += 256) {
        int dd = e >> 4, cc = e & 15;
        Bs[cc][dd] = pw[(d0 + dd) * kC + c0 + cc];
      }
    }
    __syncthreads();
#pragma unroll
    for (int kk = 0; kk < 16; kk++) {
      float4 a = *(const float4*)&As[kk][ty * 4];
      float4 w = *(const float4*)&Bs[kk][tx * 4];
      acc[0][0] += a.x * w.x; acc[0][1] += a.x * w.y; acc[0][2] += a.x * w.z; acc[0][3] += a.x * w.w;
      acc[1][0] += a.y * w.x; acc[1][1] += a.y * w.y; acc[1][2] += a.y * w.z; acc[1][3] += a.y * w.w;
      acc[2][0] += a.z * w.x; acc[2][1] += a.z * w.y; acc[2][2] += a.z * w.z; acc[2][3] += a.z * w.w;
      acc[3][0] += a.w * w.x; acc[3][1] += a.w * w.y; acc[3][2] += a.w * w.z; acc[3][3] += a.w * w.w;
    }
  }

  {
    float4 pb4 = *(const float4*)(pb + d0 + tx * 4);
#pragma unroll
    for (int i = 0; i < 4; i++) {
      float4 v;
      v.x = acc[i][0] + pb4.x;
      v.y = acc[i][1] + pb4.y;
      v.z = acc[i][2] + pb4.z;
      v.w = acc[i][3] + pb4.w;
      *(float4*)&S[ty * 4 + i][tx * 4] = v;
    }
    const float* textb = text + (size_t)b * kL * kD + d0;
    int e = t;
#pragma unroll
    for (int i = 0; i < 20; i++, e += 256) {
      int n = e >> 6, dd = e & 63;
      Ts[n][dd] = textb[n * kD + dd];
    }
  }
  __syncthreads();

  {
    const int task = t >> 1;
    const int half = t & 1;
    const int pp   = task & 63;
    const int mh   = task >> 6;

    float4 sv[8];
    const float* Srow = &S[pp][mh * 32];
#pragma unroll
    for (int c4 = 0; c4 < 8; c4++) sv[c4] = *(const float4*)(Srow + c4 * 4);

    float best = -3.4e38f;
    const int n0 = half * 40;
    for (int n = n0; n < n0 + 40; n++) {
      const float* Trow = &Ts[n][mh * 32];
      float sum = 0.f;
#pragma unroll
      for (int c4 = 0; c4 < 8; c4++) {
        float4 tv = *(const float4*)(Trow + c4 * 4);
        sum += sv[c4].x * tv.x + sv[c4].y * tv.y + sv[c4].z * tv.z + sv[c4].w * tv.w;
      }
      best = fmaxf(best, sum);
    }
    best = fmaxf(best, __shfl_xor(best, 1));
    if (half == 0) {
      const int m = z * 2 + mh;
      float v = best * 0.17677669529663687f + bias[m];
      v = scale[m] / (1.0f + expf(-v));
      attn_out[((size_t)b * kNH + m) * kP + p0 + pp] = v;
    }
  }
}

// ---------------------------------------------------------------------------
// Kernel 2 (MFMA): 3x3 conv (pad 1) + BN + attn gate, bf16 implicit GEMM.
// Block: 4 waves, tile = 4 rows x 64 cols (256 px) x 64 co.
// Wave w handles output row h0+w (64 px) x 64 co via 4x4 mfma_16x16x32 tiles.
// K loop: 8 ci-chunks of 32; per chunk stage img halo tile + all 9 tap weights.
// LDS ci stride padded 32->40 (80 B) for conflict-free 16B-aligned b128 reads.
// ---------------------------------------------------------------------------
__global__ __launch_bounds__(256) void conv_mfma_kernel(
    const ushort_t* __restrict__ imgT,  // (B, P, C) bf16
    const ushort_t* __restrict__ w2,    // [tap][co][ci] bf16
    const float* __restrict__ gamma,
    const float* __restrict__ beta,
    const float* __restrict__ mean,
    const float* __restrict__ var,
    const float* __restrict__ attn,     // (B, NH, P) fp32
    float* __restrict__ out) {          // (B, C, H, W) fp32
  __shared__ ushort_t Al[6 * 66 * 40];  // img: 6 rows x 66 cols x 40(ci pad) = 31680 B
  __shared__ ushort_t Wl[9 * 64 * 40];  // wgt: 9 taps x 64 co x 40(ci pad)  = 46080 B

  const int b   = blockIdx.x;
  const int h0  = blockIdx.y * 4;
  const int co0 = blockIdx.z * 64;
  const int t   = threadIdx.x;
  const int w   = t >> 6;        // wave id = output row within tile
  const int lane = t & 63;
  const int lr  = lane & 15;
  const int lq  = lane >> 4;

  const ushort_t* imgTb = imgT + (size_t)b * kP * kC;

  f32x4 acc[4][4] = {};          // [mt=co/16][nt=px/16]

  for (int kc = 0; kc < kC; kc += 32) {
    __syncthreads();
    // ---- stage img halo tile: rows h0-1..h0+4, cols -1..64, 32 ci (as 4x 16B units)
    for (int e = t; e < 6 * 66 * 4; e += 256) {
      int r   = e / 264;
      int rem = e - r * 264;
      int c   = rem >> 2;
      int cq  = (rem & 3) * 8;
      int row = h0 - 1 + r;
      uint4 v = make_uint4(0, 0, 0, 0);
      if (row >= 0 && row < kH && c >= 1 && c <= 64) {
        int px = row * kW + (c - 1);
        v = *(const uint4*)&imgTb[(size_t)px * kC + kc + cq];
      }
      *(uint4*)&Al[(r * 66 + c) * 40 + cq] = v;
    }
    // ---- stage weights: 9 taps x 64 co x 32 ci
    {
      int e = t;
#pragma unroll
      for (int i = 0; i < 9; i++, e += 256) {   // 2304 units
        int cq  = (e & 3) * 8;
        int co  = (e >> 2) & 63;
        int tap = e >> 8;
        uint4 v = *(const uint4*)&w2[((size_t)(tap * kC + co0 + co)) * kC + kc + cq];
        *(uint4*)&Wl[(tap * 64 + co) * 40 + cq] = v;
      }
    }
    __syncthreads();

    const int abase = (w * 66 + lr) * 40 + lq * 8;   // img frag base (row w, col lr)
    const int wbase = lr * 40 + lq * 8;              // wgt frag base (co lr)
#pragma unroll
    for (int tap = 0; tap < 9; tap++) {
      const int kh = tap / 3, kw = tap % 3;
      short8 bi[4];  // img B-frags (n = px col)
#pragma unroll
      for (int nt = 0; nt < 4; nt++)
        bi[nt] = *(const short8*)&Al[abase + (kh * 66 + kw + nt * 16) * 40];
      short8 aw[4];  // weight A-frags (m = co)
#pragma unroll
      for (int mt = 0; mt < 4; mt++)
        aw[mt] = *(const short8*)&Wl[wbase + (tap * 64 + mt * 16) * 40];
#pragma unroll
      for (int mt = 0; mt < 4; mt++)
#pragma unroll
        for (int nt = 0; nt < 4; nt++)
          acc[mt][nt] = __builtin_amdgcn_mfma_f32_16x16x32_bf16(
              aw[mt], bi[nt], acc[mt][nt], 0, 0, 0);
    }
  }

  // ---- epilogue: BN affine + per-head attn gate; coalesced 64B store groups
  const int h = h0 + w;
  float* outb = out + (size_t)b * kC * kP + h * kW;
#pragma unroll
  for (int mt = 0; mt < 4; mt++) {
    const int head = (co0 + mt * 16) >> 5;
    const float* arow = attn + ((size_t)(b * kNH + head)) * kP + h * kW;
    float inv_v[4], bb_v[4];
#pragma unroll
    for (int reg = 0; reg < 4; reg++) {
      int co = co0 + mt * 16 + lq * 4 + reg;
      float inv = gamma[co] * rsqrtf(var[co] + 1e-3f);
      inv_v[reg] = inv;
      bb_v[reg]  = beta[co] - mean[co] * inv;
    }
#pragma unroll
    for (int nt = 0; nt < 4; nt++) {
      const int col = nt * 16 + lr;
      const float av = arow[col];
#pragma unroll
      for (int reg = 0; reg < 4; reg++) {
        int co = co0 + mt * 16 + lq * 4 + reg;
        outb[(size_t)co * kP + col] = (acc[mt][nt][reg] * inv_v[reg] + bb_v[reg]) * av;
      }
    }
  }
}

// ---------------------------------------------------------------------------
extern "C" void kernel_launch(void* const* d_in, const int* in_sizes, int n_in,
                              void* d_out, int out_size, void* d_ws, size_t ws_size,
                              hipStream_t stream) {
  const float* img   = (const float*)d_in[0];
  const float* text  = (const float*)d_in[1];
  const float* pw    = (const float*)d_in[2];
  const float* pb    = (const float*)d_in[3];
  const float* bias  = (const float*)d_in[4];
  const float* scale = (const float*)d_in[5];
  const float* cw    = (const float*)d_in[6];
  const float* gam   = (const float*)d_in[7];
  const float* bet   = (const float*)d_in[8];
  const float* mea   = (const float*)d_in[9];
  const float* va    = (const float*)d_in[10];
  float* out = (float*)d_out;

  char* ws = (char*)d_ws;
  float*    attn = (float*)ws;                              // 8*8*4096*4   = 1 MiB
  ushort_t* imgT = (ushort_t*)(ws + (1u << 20));            // 8*4096*256*2 = 16 MiB
  ushort_t* w2   = (ushort_t*)(ws + (1u << 20) + (16u << 20)); // 9*256*256*2 = 1.125 MiB

  // NHWC bf16 transpose of img
  {
    dim3 grid(kB, kP / 64, kC / 64);
    transpose_img_kernel<<<grid, 256, 0, stream>>>(img, imgT);
  }
  // conv weight relayout [tap][co][ci] bf16
  transpose_w2_kernel<<<(9 * kC * kC + 255) / 256, 256, 0, stream>>>(cw, w2);

  // attention map (fp32)
  {
    dim3 grid(kB, kP / 64, 4);
    attn_kernel<<<grid, 256, 0, stream>>>(img, text, pw, pb, bias, scale, attn);
  }

  // 3x3 conv + BN + gate (bf16 MFMA)
  {
    dim3 grid(kB, kH / 4, kC / 64);
    conv_mfma_kernel<<<grid, 256, 0, stream>>>(imgT, w2, gam, bet, mea, va, attn, out);
  }
}

// Round 3
// 182.371 us; speedup vs baseline: 4.1270x; 1.5126x over previous
//
#include <hip/hip_runtime.h>
#include <cmath>

constexpr int kB  = 8;
constexpr int kC  = 256;
constexpr int kH  = 64;
constexpr int kW  = 64;
constexpr int kP  = kH * kW;    // 4096
constexpr int kL  = 80;
constexpr int kD  = 256;
constexpr int kNH = 8;

typedef short  short8 __attribute__((ext_vector_type(8)));
typedef float  f32x4  __attribute__((ext_vector_type(4)));
typedef unsigned short ushort_t;

// round-to-nearest-even f32 -> bf16 bits
__device__ __forceinline__ ushort_t f2bf(float f) {
  unsigned u = __builtin_bit_cast(unsigned, f);
  u += 0x7fffu + ((u >> 16) & 1u);
  return (ushort_t)(u >> 16);
}

// pack 8 fp32 (two float4) -> short8 bf16 frag
__device__ __forceinline__ short8 pack8(float4 a, float4 b) {
  ushort_t tmp[8] = {f2bf(a.x), f2bf(a.y), f2bf(a.z), f2bf(a.w),
                     f2bf(b.x), f2bf(b.y), f2bf(b.z), f2bf(b.w)};
  return *(short8*)tmp;
}

// ---------------------------------------------------------------------------
// Kernel A: img (B, C, H, W) fp32  ->  imgT (B, P, C) bf16   (NHWC cast)
// ---------------------------------------------------------------------------
__global__ __launch_bounds__(256) void transpose_img_kernel(
    const float* __restrict__ img, ushort_t* __restrict__ imgT) {
  __shared__ float Ls[64 * 67];
  const int b   = blockIdx.x;
  const int p0  = blockIdx.y * 64;
  const int ci0 = blockIdx.z * 64;
  const int t   = threadIdx.x;

  for (int e = t; e < 4096; e += 256) {
    int ci = e >> 6, px = e & 63;
    Ls[px * 67 + ci] = img[((size_t)(b * kC + ci0 + ci)) * kP + p0 + px];
  }
  __syncthreads();
  for (int u = t; u < 512; u += 256) {
    int px = u >> 3, cq = (u & 7) * 8;
    ushort_t tmp[8];
#pragma unroll
    for (int j = 0; j < 8; j++) tmp[j] = f2bf(Ls[px * 67 + cq + j]);
    *(uint4*)&imgT[((size_t)(b * kP + p0 + px)) * kC + ci0 + cq] = *(uint4*)tmp;
  }
}

// ---------------------------------------------------------------------------
// Kernel B: conv_w (co, ci, 3, 3) fp32 -> w2[tap][co][ci] bf16
// ---------------------------------------------------------------------------
__global__ __launch_bounds__(256) void transpose_w2_kernel(
    const float* __restrict__ cw, ushort_t* __restrict__ w2) {
  int idx = blockIdx.x * 256 + threadIdx.x;
  if (idx >= 9 * kC * kC) return;
  int ci  = idx & 255;
  int co  = (idx >> 8) & 255;
  int tap = idx >> 16;
  w2[idx] = f2bf(cw[(co * kC + ci) * 9 + tap]);
}

// ---------------------------------------------------------------------------
// Kernel 1 (MFMA): fused 1x1 conv + max-sigmoid attention.
// Grid (B, P/64). 4 waves; wave w owns d in [64w, 64w+64) = heads {2w, 2w+1}.
// GEMM1: A = pw rows (global fp32 -> bf16 inline), B = imgT rows (bf16 direct).
// i_feat -> LDS [px][d] bf16 (per-wave-private d range: NO barrier needed).
// Stage2 per head: 5 token m-tiles x 4 px n-tiles, K=32 = 1 MFMA each;
// max over tokens via regs + shfl_xor(16,32); sigmoid*scale; coalesced store.
// ---------------------------------------------------------------------------
__global__ __launch_bounds__(256) void attn_mfma_kernel(
    const ushort_t* __restrict__ imgT,  // (B, P, C) bf16
    const float* __restrict__ text,     // (B, L, D) fp32
    const float* __restrict__ pw,       // (D, C) fp32
    const float* __restrict__ pb,       // (D,)
    const float* __restrict__ bias,     // (NH,)
    const float* __restrict__ scale,    // (NH,)
    float* __restrict__ attn_out) {     // (B, NH, P)
  __shared__ ushort_t SI[64 * 264];     // i_feat [px][d], pad 256->264 (33792 B)

  const int b    = blockIdx.x;
  const int p0   = blockIdx.y * 64;
  const int t    = threadIdx.x;
  const int w    = t >> 6;
  const int lane = t & 63;
  const int lr   = lane & 15;
  const int lq   = lane >> 4;
  const int d0   = w * 64;

  const ushort_t* imgTb = imgT + (size_t)b * kP * kC;

  f32x4 acc[4][4] = {};   // [mt=d/16][nt=px/16]

  // ---- GEMM1: i_feat[d][px] over K=256
  for (int kc = 0; kc < kC; kc += 32) {
    short8 afr[4], bfr[4];
#pragma unroll
    for (int mt = 0; mt < 4; mt++) {
      const float* p = pw + (size_t)(d0 + mt * 16 + lr) * kC + kc + lq * 8;
      afr[mt] = pack8(*(const float4*)p, *(const float4*)(p + 4));
    }
#pragma unroll
    for (int nt = 0; nt < 4; nt++)
      bfr[nt] = *(const short8*)&imgTb[(size_t)(p0 + nt * 16 + lr) * kC + kc + lq * 8];
#pragma unroll
    for (int mt = 0; mt < 4; mt++)
#pragma unroll
      for (int nt = 0; nt < 4; nt++)
        acc[mt][nt] = __builtin_amdgcn_mfma_f32_16x16x32_bf16(afr[mt], bfr[nt], acc[mt][nt], 0, 0, 0);
  }

  // ---- epilogue: + proj bias, write i_feat tile to LDS as bf16 [px][d]
#pragma unroll
  for (int mt = 0; mt < 4; mt++) {
    float4 pb4 = *(const float4*)(pb + d0 + mt * 16 + lq * 4);
#pragma unroll
    for (int nt = 0; nt < 4; nt++) {
      ushort_t v[4];
      v[0] = f2bf(acc[mt][nt][0] + pb4.x);
      v[1] = f2bf(acc[mt][nt][1] + pb4.y);
      v[2] = f2bf(acc[mt][nt][2] + pb4.z);
      v[3] = f2bf(acc[mt][nt][3] + pb4.w);
      // px = nt*16+lr (col), d = d0 + mt*16 + lq*4 (+reg)
      *(ulonglong1*)&SI[(nt * 16 + lr) * 264 + d0 + mt * 16 + lq * 4] = *(ulonglong1*)v;
    }
  }
  // no __syncthreads(): wave w reads exactly the d-range it wrote.

  // ---- stage 2: per head, S[token][px], max over tokens, sigmoid, store
  const float* textb = text + (size_t)b * kL * kD;
#pragma unroll
  for (int lh = 0; lh < 2; lh++) {
    const int h = 2 * w + lh;
    const float bh = bias[h], sh = scale[h];
    short8 atok[5];
#pragma unroll
    for (int mt = 0; mt < 5; mt++) {
      const float* p = textb + (size_t)(mt * 16 + lr) * kD + h * 32 + lq * 8;
      atok[mt] = pack8(*(const float4*)p, *(const float4*)(p + 4));
    }
#pragma unroll
    for (int nt = 0; nt < 4; nt++) {
      short8 bfr2 = *(const short8*)&SI[(nt * 16 + lr) * 264 + h * 32 + lq * 8];
      float vmax = -3.4e38f;
#pragma unroll
      for (int mt = 0; mt < 5; mt++) {
        f32x4 z = {};
        f32x4 d = __builtin_amdgcn_mfma_f32_16x16x32_bf16(atok[mt], bfr2, z, 0, 0, 0);
        vmax = fmaxf(vmax, fmaxf(fmaxf(d[0], d[1]), fmaxf(d[2], d[3])));
      }
      vmax = fmaxf(vmax, __shfl_xor(vmax, 16));
      vmax = fmaxf(vmax, __shfl_xor(vmax, 32));
      if (lq == 0) {
        float lg = vmax * 0.17677669529663687f + bh;  // 1/sqrt(32)
        float a  = sh / (1.0f + expf(-lg));
        attn_out[((size_t)(b * kNH + h)) * kP + p0 + nt * 16 + lr] = a;
      }
    }
  }
}

// ---------------------------------------------------------------------------
// Kernel 2 (MFMA): 3x3 conv (pad 1) + BN + attn gate, bf16 implicit GEMM.
// ---------------------------------------------------------------------------
__global__ __launch_bounds__(256) void conv_mfma_kernel(
    const ushort_t* __restrict__ imgT,  // (B, P, C) bf16
    const ushort_t* __restrict__ w2,    // [tap][co][ci] bf16
    const float* __restrict__ gamma,
    const float* __restrict__ beta,
    const float* __restrict__ mean,
    const float* __restrict__ var,
    const float* __restrict__ attn,     // (B, NH, P) fp32
    float* __restrict__ out) {          // (B, C, H, W) fp32
  __shared__ ushort_t Al[6 * 66 * 40];
  __shared__ ushort_t Wl[9 * 64 * 40];

  const int b   = blockIdx.x;
  const int h0  = blockIdx.y * 4;
  const int co0 = blockIdx.z * 64;
  const int t   = threadIdx.x;
  const int w   = t >> 6;
  const int lane = t & 63;
  const int lr  = lane & 15;
  const int lq  = lane >> 4;

  const ushort_t* imgTb = imgT + (size_t)b * kP * kC;

  f32x4 acc[4][4] = {};

  for (int kc = 0; kc < kC; kc += 32) {
    __syncthreads();
    for (int e = t; e < 6 * 66 * 4; e += 256) {
      int r   = e / 264;
      int rem = e - r * 264;
      int c   = rem >> 2;
      int cq  = (rem & 3) * 8;
      int row = h0 - 1 + r;
      uint4 v = make_uint4(0, 0, 0, 0);
      if (row >= 0 && row < kH && c >= 1 && c <= 64) {
        int px = row * kW + (c - 1);
        v = *(const uint4*)&imgTb[(size_t)px * kC + kc + cq];
      }
      *(uint4*)&Al[(r * 66 + c) * 40 + cq] = v;
    }
    {
      int e = t;
#pragma unroll
      for (int i = 0; i < 9; i++, e += 256) {
        int cq  = (e & 3) * 8;
        int co  = (e >> 2) & 63;
        int tap = e >> 8;
        uint4 v = *(const uint4*)&w2[((size_t)(tap * kC + co0 + co)) * kC + kc + cq];
        *(uint4*)&Wl[(tap * 64 + co) * 40 + cq] = v;
      }
    }
    __syncthreads();

    const int abase = (w * 66 + lr) * 40 + lq * 8;
    const int wbase = lr * 40 + lq * 8;
#pragma unroll
    for (int tap = 0; tap < 9; tap++) {
      const int kh = tap / 3, kw = tap % 3;
      short8 bi[4];
#pragma unroll
      for (int nt = 0; nt < 4; nt++)
        bi[nt] = *(const short8*)&Al[abase + (kh * 66 + kw + nt * 16) * 40];
      short8 aw[4];
#pragma unroll
      for (int mt = 0; mt < 4; mt++)
        aw[mt] = *(const short8*)&Wl[wbase + (tap * 64 + mt * 16) * 40];
#pragma unroll
      for (int mt = 0; mt < 4; mt++)
#pragma unroll
        for (int nt = 0; nt < 4; nt++)
          acc[mt][nt] = __builtin_amdgcn_mfma_f32_16x16x32_bf16(
              aw[mt], bi[nt], acc[mt][nt], 0, 0, 0);
    }
  }

  const int h = h0 + w;
  float* outb = out + (size_t)b * kC * kP + h * kW;
#pragma unroll
  for (int mt = 0; mt < 4; mt++) {
    const int head = (co0 + mt * 16) >> 5;
    const float* arow = attn + ((size_t)(b * kNH + head)) * kP + h * kW;
    float inv_v[4], bb_v[4];
#pragma unroll
    for (int reg = 0; reg < 4; reg++) {
      int co = co0 + mt * 16 + lq * 4 + reg;
      float inv = gamma[co] * rsqrtf(var[co] + 1e-3f);
      inv_v[reg] = inv;
      bb_v[reg]  = beta[co] - mean[co] * inv;
    }
#pragma unroll
    for (int nt = 0; nt < 4; nt++) {
      const int col = nt * 16 + lr;
      const float av = arow[col];
#pragma unroll
      for (int reg = 0; reg < 4; reg++) {
        int co = co0 + mt * 16 + lq * 4 + reg;
        outb[(size_t)co * kP + col] = (acc[mt][nt][reg] * inv_v[reg] + bb_v[reg]) * av;
      }
    }
  }
}

// ---------------------------------------------------------------------------
extern "C" void kernel_launch(void* const* d_in, const int* in_sizes, int n_in,
                              void* d_out, int out_size, void* d_ws, size_t ws_size,
                              hipStream_t stream) {
  const float* img   = (const float*)d_in[0];
  const float* text  = (const float*)d_in[1];
  const float* pw    = (const float*)d_in[2];
  const float* pb    = (const float*)d_in[3];
  const float* bias  = (const float*)d_in[4];
  const float* scale = (const float*)d_in[5];
  const float* cw    = (const float*)d_in[6];
  const float* gam   = (const float*)d_in[7];
  const float* bet   = (const float*)d_in[8];
  const float* mea   = (const float*)d_in[9];
  const float* va    = (const float*)d_in[10];
  float* out = (float*)d_out;

  char* ws = (char*)d_ws;
  float*    attn = (float*)ws;                                 // 1 MiB
  ushort_t* imgT = (ushort_t*)(ws + (1u << 20));               // 16 MiB
  ushort_t* w2   = (ushort_t*)(ws + (1u << 20) + (16u << 20)); // 1.125 MiB

  // NHWC bf16 transpose of img (needed by both attn and conv)
  {
    dim3 grid(kB, kP / 64, kC / 64);
    transpose_img_kernel<<<grid, 256, 0, stream>>>(img, imgT);
  }
  // conv weight relayout [tap][co][ci] bf16
  transpose_w2_kernel<<<(9 * kC * kC + 255) / 256, 256, 0, stream>>>(cw, w2);

  // attention map (bf16 MFMA)
  {
    dim3 grid(kB, kP / 64);
    attn_mfma_kernel<<<grid, 256, 0, stream>>>(imgT, text, pw, pb, bias, scale, attn);
  }

  // 3x3 conv + BN + gate (bf16 MFMA)
  {
    dim3 grid(kB, kH / 4, kC / 64);
    conv_mfma_kernel<<<grid, 256, 0, stream>>>(imgT, w2, gam, bet, mea, va, attn, out);
  }
}